// Round 1
// baseline (8043.198 us; speedup 1.0000x reference)
//
#include <hip/hip_runtime.h>
#include <hip/hip_bf16.h>
#include <math.h>

// Problem constants
#define Bb 4
#define Nn 4096
#define Hh 16
#define DHh 64
#define Mm 266
#define Dd 1024
#define BHh (Bb*Hh)

#define DN_SCALE 0.35355339059327373f   // 64^-0.25
#define RATIO 0.06131393394849658f      // 266^-0.5
#define EPS_FAVOR 1e-4f
#define EPS_LN 1e-5f

__device__ __forceinline__ unsigned fenc(float f) {
    unsigned u = __float_as_uint(f);
    return (u & 0x80000000u) ? ~u : (u | 0x80000000u);
}
__device__ __forceinline__ float fdec(unsigned e) {
    unsigned u = (e & 0x80000000u) ? (e ^ 0x80000000u) : ~e;
    return __uint_as_float(u);
}

// ---------------------------------------------------------------------------
// Tiled fp32 GEMM: C = A[16384,1024] @ W[1024,1024]
// mode 0: write head-major [(b*H+h)*N + n]*64 + dh, scaled by `scale`
// mode 1: write flat [r*1024 + c] = acc + bias[c] + resid[r*1024+c]
// block: 256 threads, 64x64 tile, BK=16, 4x4 per thread
// ---------------------------------------------------------------------------
__global__ __launch_bounds__(256) void gemm_tiled(
    const float* __restrict__ A, const float* __restrict__ W,
    float* __restrict__ C, const float* __restrict__ bias,
    const float* __restrict__ resid, float scale, int mode)
{
    const int tid = threadIdx.x;
    const int tx = tid & 15, ty = tid >> 4;
    const int row0 = blockIdx.y * 64, col0 = blockIdx.x * 64;

    __shared__ float As[16][64];   // [k][m]
    __shared__ float Ws[16][64];   // [k][n]

    float acc[4][4] = {};

    const int ar = tid >> 2;            // 0..63 (row in tile)
    const int ak = (tid & 3) << 2;      // 0,4,8,12
    const int wk = tid >> 4;            // 0..15
    const int wc = (tid & 15) << 2;     // 0..60

    for (int k0 = 0; k0 < Dd; k0 += 16) {
        float4 av = *(const float4*)(A + (size_t)(row0 + ar) * Dd + k0 + ak);
        float4 wv = *(const float4*)(W + (size_t)(k0 + wk) * Dd + col0 + wc);
        __syncthreads();
        As[ak + 0][ar] = av.x; As[ak + 1][ar] = av.y;
        As[ak + 2][ar] = av.z; As[ak + 3][ar] = av.w;
        *(float4*)&Ws[wk][wc] = wv;
        __syncthreads();
#pragma unroll
        for (int kk = 0; kk < 16; ++kk) {
            float a0 = As[kk][ty * 4 + 0], a1 = As[kk][ty * 4 + 1];
            float a2 = As[kk][ty * 4 + 2], a3 = As[kk][ty * 4 + 3];
            float b0 = Ws[kk][tx * 4 + 0], b1 = Ws[kk][tx * 4 + 1];
            float b2 = Ws[kk][tx * 4 + 2], b3 = Ws[kk][tx * 4 + 3];
            acc[0][0] += a0 * b0; acc[0][1] += a0 * b1; acc[0][2] += a0 * b2; acc[0][3] += a0 * b3;
            acc[1][0] += a1 * b0; acc[1][1] += a1 * b1; acc[1][2] += a1 * b2; acc[1][3] += a1 * b3;
            acc[2][0] += a2 * b0; acc[2][1] += a2 * b1; acc[2][2] += a2 * b2; acc[2][3] += a2 * b3;
            acc[3][0] += a3 * b0; acc[3][1] += a3 * b1; acc[3][2] += a3 * b2; acc[3][3] += a3 * b3;
        }
    }

    if (mode == 0) {
        // head-major output
        const int h = col0 >> 6;          // col tile == one head (64 aligned)
        const int dh = tx * 4;
#pragma unroll
        for (int i = 0; i < 4; ++i) {
            int r = row0 + ty * 4 + i;
            int b = r >> 12, n = r & (Nn - 1);
            float4 o = make_float4(acc[i][0] * scale, acc[i][1] * scale,
                                   acc[i][2] * scale, acc[i][3] * scale);
            *(float4*)(C + ((size_t)((b * Hh + h) * Nn + n)) * DHh + dh) = o;
        }
    } else {
        const int c = col0 + tx * 4;
        float4 bv = *(const float4*)(bias + c);
#pragma unroll
        for (int i = 0; i < 4; ++i) {
            int r = row0 + ty * 4 + i;
            float4 rv = *(const float4*)(resid + (size_t)r * Dd + c);
            float4 o = make_float4(acc[i][0] + bv.x + rv.x, acc[i][1] + bv.y + rv.y,
                                   acc[i][2] + bv.z + rv.z, acc[i][3] + bv.w + rv.w);
            *(float4*)(C + (size_t)r * Dd + c) = o;
        }
    }
}

// ---------------------------------------------------------------------------
// k-stab: per (b,h), max over all (n,m) of ks[n,:]·proj[m,:]
// grid: (BH, N/64), block 256
// ---------------------------------------------------------------------------
__global__ __launch_bounds__(256) void kstab_kernel(
    const float* __restrict__ ks, const float* __restrict__ proj,
    unsigned* __restrict__ stab_enc)
{
    const int bh = blockIdx.x;
    const int n0 = blockIdx.y * 64;
    const int tid = threadIdx.x;

    __shared__ float kt[64][65];
    __shared__ float red[256];

#pragma unroll
    for (int t = 0; t < 4; ++t) {
        int fi = tid + t * 256;             // 1024 float4 total
        int r = fi >> 4, k4 = (fi & 15) << 2;
        float4 a = *(const float4*)(ks + ((size_t)(bh * Nn) + n0 + r) * DHh + k4);
        kt[r][k4 + 0] = a.x; kt[r][k4 + 1] = a.y; kt[r][k4 + 2] = a.z; kt[r][k4 + 3] = a.w;
    }
    __syncthreads();

    float mx = -3.0e38f;
    for (int idx = tid; idx < 64 * Mm; idx += 256) {
        int n = idx & 63, m = idx >> 6;
        const float* pr = proj + m * DHh;
        float s = 0.f;
#pragma unroll 8
        for (int k = 0; k < 64; ++k) s += kt[n][k] * pr[k];
        mx = fmaxf(mx, s);
    }
    red[tid] = mx;
    __syncthreads();
    for (int off = 128; off > 0; off >>= 1) {
        if (tid < off) red[tid] = fmaxf(red[tid], red[tid + off]);
        __syncthreads();
    }
    if (tid == 0) atomicMax(stab_enc + bh, fenc(red[0]));
}

// ---------------------------------------------------------------------------
// ctx kernel: ctx[bh][m][d] = sum_n kf[n][m]*v[n][d]; ksum[bh][m] = sum_n kf
// grid: (5 mchunks, 4 nsplits, 64 bh), block 256
// ---------------------------------------------------------------------------
__global__ __launch_bounds__(256) void ctx_kernel(
    const float* __restrict__ ks, const float* __restrict__ vv,
    const float* __restrict__ proj, const unsigned* __restrict__ stab_enc,
    float* __restrict__ ctx, float* __restrict__ ksum)
{
    const int m0 = blockIdx.x * 64;
    const int nb = blockIdx.y;
    const int bh = blockIdx.z;
    const int tid = threadIdx.x;
    const int tx = tid & 63, ty = tid >> 6;
    const float kst = fdec(stab_enc[bh]);

    __shared__ float kt[32][65];
    __shared__ float vt[32][65];
    __shared__ float kf[32][65];
    __shared__ float diag[32];

    float acc[16] = {};
    float ksacc = 0.f;

    const int n_begin = nb * (Nn / 4);
    for (int nt = n_begin; nt < n_begin + (Nn / 4); nt += 32) {
#pragma unroll
        for (int t = 0; t < 2; ++t) {
            int fi = tid + t * 256;             // 512 float4 per tile
            int r = fi >> 4, k4 = (fi & 15) << 2;
            float4 a = *(const float4*)(ks + ((size_t)(bh * Nn) + nt + r) * DHh + k4);
            kt[r][k4 + 0] = a.x; kt[r][k4 + 1] = a.y; kt[r][k4 + 2] = a.z; kt[r][k4 + 3] = a.w;
            float4 b = *(const float4*)(vv + ((size_t)(bh * Nn) + nt + r) * DHh + k4);
            vt[r][k4 + 0] = b.x; vt[r][k4 + 1] = b.y; vt[r][k4 + 2] = b.z; vt[r][k4 + 3] = b.w;
        }
        __syncthreads();
        if (tid < 32) {
            float s = 0.f;
#pragma unroll 8
            for (int k = 0; k < 64; ++k) s += kt[tid][k] * kt[tid][k];
            diag[tid] = 0.5f * s;
        }
        __syncthreads();
        // features for this tile: 32 n x 64 m_local
#pragma unroll
        for (int t = 0; t < 8; ++t) {
            int idx = tid + t * 256;
            int n = idx & 31, ml = idx >> 5;
            int m = m0 + ml;
            float val = 0.f;
            if (m < Mm) {
                const float* pr = proj + m * DHh;
                float s = 0.f;
#pragma unroll 8
                for (int k = 0; k < 64; ++k) s += kt[n][k] * pr[k];
                val = RATIO * (__expf(s - diag[n] - kst) + EPS_FAVOR);
            }
            kf[n][ml] = val;
        }
        __syncthreads();
        // accumulate ctx
        for (int n = 0; n < 32; ++n) {
            float vr = vt[n][tx];
#pragma unroll
            for (int j = 0; j < 16; ++j) acc[j] += kf[n][ty + j * 4] * vr;
        }
        if (ty == 0) {
            for (int n = 0; n < 32; ++n) ksacc += kf[n][tx];
        }
        __syncthreads();
    }

#pragma unroll
    for (int j = 0; j < 16; ++j) {
        int m = m0 + ty + j * 4;
        if (m < Mm) atomicAdd(&ctx[((size_t)bh * Mm + m) * DHh + tx], acc[j]);
    }
    if (ty == 0 && (m0 + tx) < Mm) atomicAdd(&ksum[(size_t)bh * Mm + m0 + tx], ksacc);
}

// ---------------------------------------------------------------------------
// q-side: features -> row stab -> exp -> d_inv -> out = (qf @ ctx) * d_inv
// grid: (N/32, BH), block 256
// ---------------------------------------------------------------------------
__global__ __launch_bounds__(256) void qout_kernel(
    const float* __restrict__ qs, const float* __restrict__ proj,
    const float* __restrict__ ctx, const float* __restrict__ ksum,
    float* __restrict__ attn)
{
    const int n0 = blockIdx.x * 32;
    const int bh = blockIdx.y;
    const int b = bh >> 4, h = bh & 15;
    const int tid = threadIdx.x;

    __shared__ float qt[32][65];
    __shared__ float qf[32][267];
    __shared__ float diag[32], stab[32], dinv[32];
    __shared__ float red[256];

#pragma unroll
    for (int t = 0; t < 2; ++t) {
        int fi = tid + t * 256;
        int r = fi >> 4, k4 = (fi & 15) << 2;
        float4 a = *(const float4*)(qs + ((size_t)(bh * Nn) + n0 + r) * DHh + k4);
        qt[r][k4 + 0] = a.x; qt[r][k4 + 1] = a.y; qt[r][k4 + 2] = a.z; qt[r][k4 + 3] = a.w;
    }
    __syncthreads();
    if (tid < 32) {
        float s = 0.f;
#pragma unroll 8
        for (int k = 0; k < 64; ++k) s += qt[tid][k] * qt[tid][k];
        diag[tid] = 0.5f * s;
    }
    __syncthreads();

    // raw features qd -> qf (32 x 266)
    for (int idx = tid; idx < 32 * Mm; idx += 256) {
        int n = idx & 31, m = idx >> 5;
        const float* pr = proj + m * DHh;
        float s = 0.f;
#pragma unroll 8
        for (int k = 0; k < 64; ++k) s += qt[n][k] * pr[k];
        qf[n][m] = s;
    }
    __syncthreads();

    const int r = tid & 31, g = tid >> 5;   // 32 rows x 8 groups
    float mx = -3.0e38f;
    for (int m = g; m < Mm; m += 8) mx = fmaxf(mx, qf[r][m]);
    red[tid] = mx;
    __syncthreads();
    if (tid < 32) {
        float s = red[tid];
#pragma unroll
        for (int gg = 1; gg < 8; ++gg) s = fmaxf(s, red[gg * 32 + tid]);
        stab[tid] = s;
    }
    __syncthreads();

    float ds = 0.f;
    {
        float dg = diag[r], st = stab[r];
        for (int m = g; m < Mm; m += 8) {
            float val = RATIO * (__expf(qf[r][m] - dg - st) + EPS_FAVOR);
            qf[r][m] = val;
            ds += val * ksum[(size_t)bh * Mm + m];
        }
    }
    red[tid] = ds;
    __syncthreads();
    if (tid < 32) {
        float s = 0.f;
#pragma unroll
        for (int gg = 0; gg < 8; ++gg) s += red[gg * 32 + tid];
        dinv[tid] = 1.0f / s;
    }
    __syncthreads();

    // out[n][dh] = sum_m qf[n][m] * ctx[m][dh]
    const int tx = tid & 63, ty = tid >> 6;
    float acc8[8] = {};
    for (int m = 0; m < Mm; ++m) {
        float c = ctx[((size_t)bh * Mm + m) * DHh + tx];
#pragma unroll
        for (int t = 0; t < 8; ++t) acc8[t] += qf[ty * 8 + t][m] * c;
    }
#pragma unroll
    for (int t = 0; t < 8; ++t) {
        int n = ty * 8 + t;
        attn[((size_t)(b * Nn + n0 + n)) * Dd + h * DHh + tx] = acc8[t] * dinv[n];
    }
}

// ---------------------------------------------------------------------------
// LayerNorm: one block per row of 1024
// ---------------------------------------------------------------------------
__global__ __launch_bounds__(256) void ln_kernel(
    const float* __restrict__ y, const float* __restrict__ gamma,
    const float* __restrict__ beta, float* __restrict__ out)
{
    const int row = blockIdx.x;
    const int tid = threadIdx.x;
    float4 v = *(const float4*)(y + (size_t)row * Dd + tid * 4);
    float s = v.x + v.y + v.z + v.w;
    float q = v.x * v.x + v.y * v.y + v.z * v.z + v.w * v.w;
    __shared__ float rs[256], rq[256];
    rs[tid] = s; rq[tid] = q;
    __syncthreads();
    for (int off = 128; off > 0; off >>= 1) {
        if (tid < off) { rs[tid] += rs[tid + off]; rq[tid] += rq[tid + off]; }
        __syncthreads();
    }
    float mu = rs[0] * (1.0f / Dd);
    float var = rq[0] * (1.0f / Dd) - mu * mu;
    float rstd = rsqrtf(var + EPS_LN);
    float4 gm = *(const float4*)(gamma + tid * 4);
    float4 bt = *(const float4*)(beta + tid * 4);
    float4 o;
    o.x = (v.x - mu) * rstd * gm.x + bt.x;
    o.y = (v.y - mu) * rstd * gm.y + bt.y;
    o.z = (v.z - mu) * rstd * gm.z + bt.z;
    o.w = (v.w - mu) * rstd * gm.w + bt.w;
    *(float4*)(out + (size_t)row * Dd + tid * 4) = o;
}

// ---------------------------------------------------------------------------
extern "C" void kernel_launch(void* const* d_in, const int* in_sizes, int n_in,
                              void* d_out, int out_size, void* d_ws, size_t ws_size,
                              hipStream_t stream) {
    const float* x     = (const float*)d_in[0];
    const float* Wq    = (const float*)d_in[1];
    const float* Wk    = (const float*)d_in[2];
    const float* Wv    = (const float*)d_in[3];
    const float* Wo    = (const float*)d_in[4];
    const float* bo    = (const float*)d_in[5];
    const float* proj  = (const float*)d_in[6];
    const float* gamma = (const float*)d_in[7];
    const float* beta  = (const float*)d_in[8];
    float* out = (float*)d_out;

    float* ws = (float*)d_ws;
    const size_t S1 = (size_t)BHh * Nn * DHh;   // 16,777,216
    float* qs   = ws;                // also reused as yresid after qout
    float* ks   = ws + S1;
    float* vv   = ws + 2 * S1;       // reused as attn output (token-major)
    float* ctx  = ws + 3 * S1;                      // BH*M*64
    float* ksum = ctx + (size_t)BHh * Mm * DHh;     // BH*M
    unsigned* stab_enc = (unsigned*)(ksum + (size_t)BHh * Mm);  // BH

    hipMemsetAsync(ctx, 0, (size_t)BHh * Mm * DHh * sizeof(float), stream);
    hipMemsetAsync(ksum, 0, (size_t)BHh * Mm * sizeof(float), stream);
    hipMemsetAsync(stab_enc, 0, BHh * sizeof(unsigned), stream);

    dim3 ggrid(Dd / 64, (Bb * Nn) / 64);
    gemm_tiled<<<ggrid, 256, 0, stream>>>(x, Wq, qs, nullptr, nullptr, DN_SCALE, 0);
    gemm_tiled<<<ggrid, 256, 0, stream>>>(x, Wk, ks, nullptr, nullptr, DN_SCALE, 0);
    gemm_tiled<<<ggrid, 256, 0, stream>>>(x, Wv, vv, nullptr, nullptr, 1.0f, 0);

    kstab_kernel<<<dim3(BHh, Nn / 64), 256, 0, stream>>>(ks, proj, stab_enc);

    ctx_kernel<<<dim3(5, 4, BHh), 256, 0, stream>>>(ks, vv, proj, stab_enc, ctx, ksum);

    // attn written into vv region (v no longer needed)
    float* attn = vv;
    qout_kernel<<<dim3(Nn / 32, BHh), 256, 0, stream>>>(qs, proj, ctx, ksum, attn);

    // yresid = attn @ Wo + bo + x, written into qs region
    gemm_tiled<<<ggrid, 256, 0, stream>>>(attn, Wo, qs, bo, x, 1.0f, 1);

    ln_kernel<<<Bb * Nn, 256, 0, stream>>>(qs, gamma, beta, out);
}

// Round 3
// 5467.093 us; speedup vs baseline: 1.4712x; 1.4712x over previous
//
#include <hip/hip_runtime.h>
#include <hip/hip_bf16.h>
#include <math.h>

// Problem constants
#define Bb 4
#define Nn 4096
#define Hh 16
#define DHh 64
#define Mm 266
#define Dd 1024
#define BHh (Bb*Hh)

#define DN_SCALE 0.35355339059327373f   // 64^-0.25
#define RATIO 0.06131393394849658f      // 266^-0.5
#define EPS_FAVOR 1e-4f
#define EPS_LN 1e-5f

typedef __attribute__((ext_vector_type(8))) short frag_t;   // 8 x bf16
typedef __attribute__((ext_vector_type(4))) float f32x4;

__device__ __forceinline__ ushort f2bf(float f) {
    unsigned u = __float_as_uint(f);
    return (ushort)((u + 0x7FFFu + ((u >> 16) & 1u)) >> 16);
}
__device__ __forceinline__ float bf2f(ushort h) {
    return __uint_as_float(((unsigned)h) << 16);
}
__device__ __forceinline__ unsigned fenc(float f) {
    unsigned u = __float_as_uint(f);
    return (u & 0x80000000u) ? ~u : (u | 0x80000000u);
}
__device__ __forceinline__ float fdec(unsigned e) {
    unsigned u = (e & 0x80000000u) ? (e ^ 0x80000000u) : ~e;
    return __uint_as_float(u);
}
__device__ __forceinline__ void gld16(const void* g, void* l) {
    __builtin_amdgcn_global_load_lds((const __attribute__((address_space(1))) unsigned int*)g,
                                     (__attribute__((address_space(3))) unsigned int*)l, 16, 0, 0);
}

// ---------------------------------------------------------------------------
// prep: x fp32 -> bf16
// ---------------------------------------------------------------------------
__global__ __launch_bounds__(256) void conv_x_kernel(const float* __restrict__ x,
                                                     ushort* __restrict__ xb) {
    size_t i = ((size_t)blockIdx.x * 256 + threadIdx.x) * 8;
    float4 f0 = *(const float4*)(x + i);
    float4 f1 = *(const float4*)(x + i + 4);
    uint4 o;
    o.x = (unsigned)f2bf(f0.x) | ((unsigned)f2bf(f0.y) << 16);
    o.y = (unsigned)f2bf(f0.z) | ((unsigned)f2bf(f0.w) << 16);
    o.z = (unsigned)f2bf(f1.x) | ((unsigned)f2bf(f1.y) << 16);
    o.w = (unsigned)f2bf(f1.z) | ((unsigned)f2bf(f1.w) << 16);
    *(uint4*)(xb + i) = o;
}

// prep: W[k][n] fp32 -> WT[n][k] bf16 (K-contiguous for the B^T GEMM)
__global__ __launch_bounds__(256) void conv_wt_kernel(
    const float* __restrict__ Wq, const float* __restrict__ Wk,
    const float* __restrict__ Wv, const float* __restrict__ Wo,
    ushort* __restrict__ Tq, ushort* __restrict__ Tk,
    ushort* __restrict__ Tv, ushort* __restrict__ To) {
    const int z = blockIdx.z;
    const float* W = z == 0 ? Wq : z == 1 ? Wk : z == 2 ? Wv : Wo;
    ushort* WT = z == 0 ? Tq : z == 1 ? Tk : z == 2 ? Tv : To;
    __shared__ float tls[64][65];
    const int tid = threadIdx.x;
    const int n0 = blockIdx.x * 64, k0 = blockIdx.y * 64;
    const int r = tid >> 2, seg = tid & 3;
#pragma unroll
    for (int i = 0; i < 4; ++i) {
        float4 f = *(const float4*)(W + (size_t)(k0 + r) * 1024 + n0 + seg * 16 + i * 4);
        tls[r][seg * 16 + i * 4 + 0] = f.x;
        tls[r][seg * 16 + i * 4 + 1] = f.y;
        tls[r][seg * 16 + i * 4 + 2] = f.z;
        tls[r][seg * 16 + i * 4 + 3] = f.w;
    }
    __syncthreads();
    const int nl = tid >> 2;
#pragma unroll
    for (int i = 0; i < 16; ++i)
        WT[(size_t)(n0 + nl) * 1024 + k0 + seg * 16 + i] = f2bf(tls[seg * 16 + i][nl]);
}

// ---------------------------------------------------------------------------
// bf16 MFMA GEMM (m97 pattern, no swizzle): C[16384,1024] = A @ WT^T
// mode 0: head-major bf16 out (z selects W/out/scale)  mode 1: fp32 +bias+resid
// 128x128 tile, 4 waves (2x2), BK=32, global_load_lds width=16 staging
// ---------------------------------------------------------------------------
__global__ __launch_bounds__(256) void gemm_bt(
    const ushort* __restrict__ A,
    const ushort* __restrict__ W0, const ushort* __restrict__ W1, const ushort* __restrict__ W2,
    ushort* __restrict__ o0, ushort* __restrict__ o1, ushort* __restrict__ o2,
    const float* __restrict__ bo, const float* __restrict__ xres, float* __restrict__ yres,
    int mode)
{
    __shared__ ushort As[128 * 32];
    __shared__ ushort Bs[128 * 32];
    const int tid = threadIdx.x;
    const int lane = tid & 63, w = tid >> 6;
    const int q = lane >> 4, m16 = lane & 15;
    const int wm = w & 1, wn = w >> 1;
    const int by = blockIdx.x, bx = blockIdx.y, z = blockIdx.z;
    const int row0 = by * 128, col0 = bx * 128;
    const ushort* WT = (mode == 0) ? (z == 0 ? W0 : z == 1 ? W1 : W2) : W0;

    f32x4 acc[4][4];
#pragma unroll
    for (int i = 0; i < 4; ++i)
#pragma unroll
        for (int j = 0; j < 4; ++j) acc[i][j] = (f32x4){0.f, 0.f, 0.f, 0.f};

    const int srow = lane >> 2;     // row within 16-row chunk
    const int sseg = lane & 3;      // k-segment (8 ushorts)
    const int c0i = w * 2;

    for (int k0 = 0; k0 < 1024; k0 += 32) {
        __syncthreads();
#pragma unroll
        for (int c = 0; c < 2; ++c) {
            int idx = c0i + c;
            int ra = idx * 16 + srow;
            gld16(A  + (size_t)(row0 + ra) * 1024 + k0 + sseg * 8, (void*)(As + idx * 512 + lane * 8));
            gld16(WT + (size_t)(col0 + ra) * 1024 + k0 + sseg * 8, (void*)(Bs + idx * 512 + lane * 8));
        }
        __syncthreads();
        frag_t af[4], bf[4];
#pragma unroll
        for (int t = 0; t < 4; ++t) {
            af[t] = *(const frag_t*)&As[(wm * 64 + t * 16 + m16) * 32 + q * 8];
            bf[t] = *(const frag_t*)&Bs[(wn * 64 + t * 16 + m16) * 32 + q * 8];
        }
#pragma unroll
        for (int i = 0; i < 4; ++i)
#pragma unroll
            for (int j = 0; j < 4; ++j)
                acc[i][j] = __builtin_amdgcn_mfma_f32_16x16x32_bf16(af[i], bf[j], acc[i][j], 0, 0, 0);
    }

    if (mode == 0) {
        const float scale = (z < 2) ? DN_SCALE : 1.0f;
        ushort* outp = z == 0 ? o0 : z == 1 ? o1 : o2;
#pragma unroll
        for (int i = 0; i < 4; ++i)
#pragma unroll
            for (int j = 0; j < 4; ++j)
#pragma unroll
                for (int r = 0; r < 4; ++r) {
                    int row = row0 + wm * 64 + i * 16 + q * 4 + r;
                    int col = col0 + wn * 64 + j * 16 + m16;
                    int b = row >> 12, n = row & 4095;
                    int h = col >> 6, dh = col & 63;
                    outp[((size_t)((b << 4) + h) * 4096 + n) * 64 + dh] = f2bf(acc[i][j][r] * scale);
                }
    } else {
#pragma unroll
        for (int i = 0; i < 4; ++i)
#pragma unroll
            for (int j = 0; j < 4; ++j)
#pragma unroll
                for (int r = 0; r < 4; ++r) {
                    int row = row0 + wm * 64 + i * 16 + q * 4 + r;
                    int col = col0 + wn * 64 + j * 16 + m16;
                    size_t off = (size_t)row * 1024 + col;
                    yres[off] = acc[i][j][r] + bo[col] + xres[off];
                }
    }
}

// ---------------------------------------------------------------------------
// k-stab (R1 body, bf16 loads): per (b,h) max over (n,m) of ks[n,:]·proj[m,:]
// grid: (BH, N/64), block 256
// ---------------------------------------------------------------------------
__global__ __launch_bounds__(256) void kstab_kernel(
    const ushort* __restrict__ ks, const float* __restrict__ proj,
    unsigned* __restrict__ stab_enc)
{
    const int bh = blockIdx.x;
    const int n0 = blockIdx.y * 64;
    const int tid = threadIdx.x;

    __shared__ float kt[64][65];
    __shared__ float red[256];

#pragma unroll
    for (int t = 0; t < 4; ++t) {
        int fi = tid + t * 256;             // 1024 x 4-elem loads
        int r = fi >> 4, k4 = (fi & 15) << 2;
        ushort4 a = *(const ushort4*)(ks + ((size_t)(bh * Nn) + n0 + r) * DHh + k4);
        kt[r][k4 + 0] = bf2f(a.x); kt[r][k4 + 1] = bf2f(a.y);
        kt[r][k4 + 2] = bf2f(a.z); kt[r][k4 + 3] = bf2f(a.w);
    }
    __syncthreads();

    float mx = -3.0e38f;
    for (int idx = tid; idx < 64 * Mm; idx += 256) {
        int n = idx & 63, m = idx >> 6;
        const float* pr = proj + m * DHh;
        float s = 0.f;
#pragma unroll 8
        for (int k = 0; k < 64; ++k) s += kt[n][k] * pr[k];
        mx = fmaxf(mx, s);
    }
    red[tid] = mx;
    __syncthreads();
    for (int off = 128; off > 0; off >>= 1) {
        if (tid < off) red[tid] = fmaxf(red[tid], red[tid + off]);
        __syncthreads();
    }
    if (tid == 0) atomicMax(stab_enc + bh, fenc(red[0]));
}

// ---------------------------------------------------------------------------
// ctx (R1 body, bf16 loads): ctx[bh][m][d] = sum_n kf[n][m]*v[n][d]
// grid: (5 mchunks, 4 nsplits, 64 bh), block 256
// ---------------------------------------------------------------------------
__global__ __launch_bounds__(256) void ctx_kernel(
    const ushort* __restrict__ ks, const ushort* __restrict__ vv,
    const float* __restrict__ proj, const unsigned* __restrict__ stab_enc,
    float* __restrict__ ctx, float* __restrict__ ksum)
{
    const int m0 = blockIdx.x * 64;
    const int nb = blockIdx.y;
    const int bh = blockIdx.z;
    const int tid = threadIdx.x;
    const int tx = tid & 63, ty = tid >> 6;
    const float kst = fdec(stab_enc[bh]);

    __shared__ float kt[32][65];
    __shared__ float vt[32][65];
    __shared__ float kf[32][65];
    __shared__ float diag[32];

    float acc[16] = {};
    float ksacc = 0.f;

    const int n_begin = nb * (Nn / 4);
    for (int nt = n_begin; nt < n_begin + (Nn / 4); nt += 32) {
#pragma unroll
        for (int t = 0; t < 2; ++t) {
            int fi = tid + t * 256;             // 512 x 4-elem loads per tile
            int r = fi >> 4, k4 = (fi & 15) << 2;
            ushort4 a = *(const ushort4*)(ks + ((size_t)(bh * Nn) + nt + r) * DHh + k4);
            kt[r][k4 + 0] = bf2f(a.x); kt[r][k4 + 1] = bf2f(a.y);
            kt[r][k4 + 2] = bf2f(a.z); kt[r][k4 + 3] = bf2f(a.w);
            ushort4 b = *(const ushort4*)(vv + ((size_t)(bh * Nn) + nt + r) * DHh + k4);
            vt[r][k4 + 0] = bf2f(b.x); vt[r][k4 + 1] = bf2f(b.y);
            vt[r][k4 + 2] = bf2f(b.z); vt[r][k4 + 3] = bf2f(b.w);
        }
        __syncthreads();
        if (tid < 32) {
            float s = 0.f;
#pragma unroll 8
            for (int k = 0; k < 64; ++k) s += kt[tid][k] * kt[tid][k];
            diag[tid] = 0.5f * s;
        }
        __syncthreads();
        // features for this tile: 32 n x 64 m_local
#pragma unroll
        for (int t = 0; t < 8; ++t) {
            int idx = tid + t * 256;
            int n = idx & 31, ml = idx >> 5;
            int m = m0 + ml;
            float val = 0.f;
            if (m < Mm) {
                const float* pr = proj + m * DHh;
                float s = 0.f;
#pragma unroll 8
                for (int k = 0; k < 64; ++k) s += kt[n][k] * pr[k];
                val = RATIO * (__expf(s - diag[n] - kst) + EPS_FAVOR);
            }
            kf[n][ml] = val;
        }
        __syncthreads();
        // accumulate ctx
        for (int n = 0; n < 32; ++n) {
            float vr = vt[n][tx];
#pragma unroll
            for (int j = 0; j < 16; ++j) acc[j] += kf[n][ty + j * 4] * vr;
        }
        if (ty == 0) {
            for (int n = 0; n < 32; ++n) ksacc += kf[n][tx];
        }
        __syncthreads();
    }

#pragma unroll
    for (int j = 0; j < 16; ++j) {
        int m = m0 + ty + j * 4;
        if (m < Mm) atomicAdd(&ctx[((size_t)bh * Mm + m) * DHh + tx], acc[j]);
    }
    if (ty == 0 && (m0 + tx) < Mm) atomicAdd(&ksum[(size_t)bh * Mm + m0 + tx], ksacc);
}

// ---------------------------------------------------------------------------
// q-side (R1 body, bf16 in / bf16 out): features -> stab -> exp -> d_inv ->
// attn = (qf @ ctx) * d_inv.  grid: (N/32, BH), block 256
// ---------------------------------------------------------------------------
__global__ __launch_bounds__(256) void qout_kernel(
    const ushort* __restrict__ qs, const float* __restrict__ proj,
    const float* __restrict__ ctx, const float* __restrict__ ksum,
    ushort* __restrict__ attnb)
{
    const int n0 = blockIdx.x * 32;
    const int bh = blockIdx.y;
    const int b = bh >> 4, h = bh & 15;
    const int tid = threadIdx.x;

    __shared__ float qt[32][65];
    __shared__ float qf[32][267];
    __shared__ float diag[32], stab[32], dinv[32];
    __shared__ float red[256];

#pragma unroll
    for (int t = 0; t < 2; ++t) {
        int fi = tid + t * 256;
        int r = fi >> 4, k4 = (fi & 15) << 2;
        ushort4 a = *(const ushort4*)(qs + ((size_t)(bh * Nn) + n0 + r) * DHh + k4);
        qt[r][k4 + 0] = bf2f(a.x); qt[r][k4 + 1] = bf2f(a.y);
        qt[r][k4 + 2] = bf2f(a.z); qt[r][k4 + 3] = bf2f(a.w);
    }
    __syncthreads();
    if (tid < 32) {
        float s = 0.f;
#pragma unroll 8
        for (int k = 0; k < 64; ++k) s += qt[tid][k] * qt[tid][k];
        diag[tid] = 0.5f * s;
    }
    __syncthreads();

    // raw features qd -> qf (32 x 266)
    for (int idx = tid; idx < 32 * Mm; idx += 256) {
        int n = idx & 31, m = idx >> 5;
        const float* pr = proj + m * DHh;
        float s = 0.f;
#pragma unroll 8
        for (int k = 0; k < 64; ++k) s += qt[n][k] * pr[k];
        qf[n][m] = s;
    }
    __syncthreads();

    const int r = tid & 31, g = tid >> 5;   // 32 rows x 8 groups
    float mx = -3.0e38f;
    for (int m = g; m < Mm; m += 8) mx = fmaxf(mx, qf[r][m]);
    red[tid] = mx;
    __syncthreads();
    if (tid < 32) {
        float s = red[tid];
#pragma unroll
        for (int gg = 1; gg < 8; ++gg) s = fmaxf(s, red[gg * 32 + tid]);
        stab[tid] = s;
    }
    __syncthreads();

    float ds = 0.f;
    {
        float dg = diag[r], st = stab[r];
        for (int m = g; m < Mm; m += 8) {
            float val = RATIO * (__expf(qf[r][m] - dg - st) + EPS_FAVOR);
            qf[r][m] = val;
            ds += val * ksum[(size_t)bh * Mm + m];
        }
    }
    red[tid] = ds;
    __syncthreads();
    if (tid < 32) {
        float s = 0.f;
#pragma unroll
        for (int gg = 0; gg < 8; ++gg) s += red[gg * 32 + tid];
        dinv[tid] = 1.0f / s;
    }
    __syncthreads();

    // out[n][dh] = sum_m qf[n][m] * ctx[m][dh]
    const int tx = tid & 63, ty = tid >> 6;
    float acc8[8] = {};
    for (int m = 0; m < Mm; ++m) {
        float c = ctx[((size_t)bh * Mm + m) * DHh + tx];
#pragma unroll
        for (int t = 0; t < 8; ++t) acc8[t] += qf[ty * 8 + t][m] * c;
    }
#pragma unroll
    for (int t = 0; t < 8; ++t) {
        int n = ty * 8 + t;
        attnb[((size_t)(b * Nn + n0 + n)) * Dd + h * DHh + tx] = f2bf(acc8[t] * dinv[n]);
    }
}

// ---------------------------------------------------------------------------
// LayerNorm: one block per row of 1024
// ---------------------------------------------------------------------------
__global__ __launch_bounds__(256) void ln_kernel(
    const float* __restrict__ y, const float* __restrict__ gamma,
    const float* __restrict__ beta, float* __restrict__ out)
{
    const int row = blockIdx.x;
    const int tid = threadIdx.x;
    float4 v = *(const float4*)(y + (size_t)row * Dd + tid * 4);
    float s = v.x + v.y + v.z + v.w;
    float q = v.x * v.x + v.y * v.y + v.z * v.z + v.w * v.w;
    __shared__ float rs[256], rq[256];
    rs[tid] = s; rq[tid] = q;
    __syncthreads();
    for (int off = 128; off > 0; off >>= 1) {
        if (tid < off) { rs[tid] += rs[tid + off]; rq[tid] += rq[tid + off]; }
        __syncthreads();
    }
    float mu = rs[0] * (1.0f / Dd);
    float var = rq[0] * (1.0f / Dd) - mu * mu;
    float rstd = rsqrtf(var + EPS_LN);
    float4 gm = *(const float4*)(gamma + tid * 4);
    float4 bt = *(const float4*)(beta + tid * 4);
    float4 o;
    o.x = (v.x - mu) * rstd * gm.x + bt.x;
    o.y = (v.y - mu) * rstd * gm.y + bt.y;
    o.z = (v.z - mu) * rstd * gm.z + bt.z;
    o.w = (v.w - mu) * rstd * gm.w + bt.w;
    *(float4*)(out + (size_t)row * Dd + tid * 4) = o;
}

// ---------------------------------------------------------------------------
extern "C" void kernel_launch(void* const* d_in, const int* in_sizes, int n_in,
                              void* d_out, int out_size, void* d_ws, size_t ws_size,
                              hipStream_t stream) {
    const float* x     = (const float*)d_in[0];
    const float* Wq    = (const float*)d_in[1];
    const float* Wk    = (const float*)d_in[2];
    const float* Wv    = (const float*)d_in[3];
    const float* Wo    = (const float*)d_in[4];
    const float* bo    = (const float*)d_in[5];
    const float* proj  = (const float*)d_in[6];
    const float* gamma = (const float*)d_in[7];
    const float* beta  = (const float*)d_in[8];
    float* out = (float*)d_out;

    const size_t TS = 16777216;           // tokens(16384) * 1024
    ushort* xb  = (ushort*)d_ws;          // x bf16; reused as attnb after QKV gemm
    ushort* qb  = xb + TS;
    ushort* kb  = qb + TS;
    ushort* vb  = kb + TS;
    ushort* WTq = vb + TS;
    ushort* WTk = WTq + 1048576;
    ushort* WTv = WTk + 1048576;
    ushort* WTo = WTv + 1048576;
    float*  ctx  = (float*)(WTo + 1048576);         // BH*M*64 fp32
    float*  ksum = ctx + (size_t)BHh * Mm * DHh;    // BH*M
    unsigned* stab = (unsigned*)(ksum + (size_t)BHh * Mm);
    ushort* attnb = xb;                   // token-major bf16 attn
    float*  yres  = (float*)qb;           // fp32, overlays qb+kb after qout

    hipMemsetAsync(ctx, 0, (size_t)BHh * Mm * DHh * sizeof(float), stream);
    hipMemsetAsync(ksum, 0, (size_t)BHh * Mm * sizeof(float), stream);
    hipMemsetAsync(stab, 0, BHh * sizeof(unsigned), stream);

    conv_x_kernel<<<8192, 256, 0, stream>>>(x, xb);
    conv_wt_kernel<<<dim3(16, 16, 4), 256, 0, stream>>>(Wq, Wk, Wv, Wo, WTq, WTk, WTv, WTo);

    gemm_bt<<<dim3(128, 8, 3), 256, 0, stream>>>(xb, WTq, WTk, WTv, qb, kb, vb,
                                                 nullptr, nullptr, nullptr, 0);

    kstab_kernel<<<dim3(BHh, Nn / 64), 256, 0, stream>>>(kb, proj, stab);

    ctx_kernel<<<dim3(5, 4, BHh), 256, 0, stream>>>(kb, vb, proj, stab, ctx, ksum);

    qout_kernel<<<dim3(Nn / 32, BHh), 256, 0, stream>>>(qb, proj, ctx, ksum, attnb);

    gemm_bt<<<dim3(128, 8, 1), 256, 0, stream>>>(attnb, WTo, nullptr, nullptr,
                                                 nullptr, nullptr, nullptr, bo, x, yres, 1);
    ln_kernel<<<16384, 256, 0, stream>>>(yres, gamma, beta, out);
}